// Round 2
// baseline (1456.676 us; speedup 1.0000x reference)
//
#include <hip/hip_runtime.h>
#include <cmath>

// Problem constants: B=2, S=2048, E=1024, H=16, HD=64, ROT=64 (== HD, full-head RoPE)
#define SB 2048
#define EB 1024
#define NH 16
#define HD 64

// ln(10000)/64
#define KLOG 0.14391156831212788f

// ---------------------------------------------------------------------------
// Kernel 1: qkv = x @ qkv_w^T + qkv_b, fused RoPE on q/k, scatter to
// (B,H,S,HD) layout. M=4096, N=3072, K=1024, NT GEMM (both row-major, K inner).
// 64x64 tile, 256 threads, 4x4 micro-tile, K-tile 16.
// ---------------------------------------------------------------------------
__global__ __launch_bounds__(256) void qkv_gemm_rope(
    const float* __restrict__ x, const float* __restrict__ w,
    const float* __restrict__ bias, float* __restrict__ qb,
    float* __restrict__ kb, float* __restrict__ vb) {
  __shared__ float As[16][68];  // [kk][m], pad 68 -> 16B-aligned b128 reads
  __shared__ float Bs[16][68];  // [kk][n]
  const int t = threadIdx.x;
  const int m0 = blockIdx.x * 64;
  const int n0 = blockIdx.y * 64;
  const int tx = t & 15, ty = t >> 4;
  float acc[4][4] = {};

  for (int k0 = 0; k0 < 1024; k0 += 16) {
#pragma unroll
    for (int i = 0; i < 4; i++) {
      int f = t + i * 256;           // 0..1023 (16x64 tile)
      int row = f >> 4, kk = f & 15; // coalesced along k
      As[kk][row] = x[(size_t)(m0 + row) * 1024 + k0 + kk];
      Bs[kk][row] = w[(size_t)(n0 + row) * 1024 + k0 + kk];
    }
    __syncthreads();
#pragma unroll
    for (int kk = 0; kk < 16; kk++) {
      float a[4], bv[4];
#pragma unroll
      for (int i = 0; i < 4; i++) a[i] = As[kk][ty * 4 + i];
#pragma unroll
      for (int j = 0; j < 4; j++) bv[j] = Bs[kk][tx * 4 + j];
#pragma unroll
      for (int i = 0; i < 4; i++)
#pragma unroll
        for (int j = 0; j < 4; j++) acc[i][j] += a[i] * bv[j];
    }
    __syncthreads();
  }

  // Epilogue: bias + RoPE (q,k) + scatter to (B,H,S,HD)
  const int c0 = n0 + tx * 4;      // global col, 4 consecutive cols per thread
  const int which = c0 >> 10;      // 0=q 1=k 2=v (uniform per block: n0 mult of 64)
  const int e0 = c0 & 1023;
  const int h = e0 >> 6;
  const int d0 = e0 & 63;          // multiple of 4: pairs (d0,d0+1),(d0+2,d0+3)
  float b4[4];
#pragma unroll
  for (int j = 0; j < 4; j++) b4[j] = bias[c0 + j];

  const float inv0 = expf(-(float)d0 * KLOG);        // 10000^(-d0/64)
  const float inv1 = expf(-(float)(d0 + 2) * KLOG);

#pragma unroll
  for (int i = 0; i < 4; i++) {
    int m = m0 + ty * 4 + i;
    int bb = m >> 11;        // batch
    int s = m & 2047;        // seq pos
    float v0 = acc[i][0] + b4[0];
    float v1 = acc[i][1] + b4[1];
    float v2 = acc[i][2] + b4[2];
    float v3 = acc[i][3] + b4[3];
    size_t off = ((size_t)(bb * NH + h) * SB + s) * HD + d0;
    if (which < 2) {
      float sn0, cs0, sn1, cs1;
      sincosf((float)s * inv0, &sn0, &cs0);
      sincosf((float)s * inv1, &sn1, &cs1);
      float r0 = v0 * cs0 - v1 * sn0;
      float r1 = v1 * cs0 + v0 * sn0;
      float r2 = v2 * cs1 - v3 * sn1;
      float r3 = v3 * cs1 + v2 * sn1;
      float* dst = (which == 0) ? qb : kb;
      dst[off] = r0; dst[off + 1] = r1; dst[off + 2] = r2; dst[off + 3] = r3;
    } else {
      vb[off] = v0; vb[off + 1] = v1; vb[off + 2] = v2; vb[off + 3] = v3;
    }
  }
}

// ---------------------------------------------------------------------------
// Kernel 2: flash attention, fp32. One block = one (b,h) x 64 query rows.
// K/V tiles of 64 staged in LDS; online softmax; O in registers
// (4 threads per q-row, 16 d-cols each). Writes context in (B,S,E) layout.
// ---------------------------------------------------------------------------
__global__ __launch_bounds__(256) void attn_flash(
    const float* __restrict__ qb, const float* __restrict__ kb,
    const float* __restrict__ vb, const int* __restrict__ mask,
    float* __restrict__ ctx) {
  __shared__ float Qs[64][65];
  __shared__ float Ks[64][65];
  __shared__ float Vs[64][64];
  __shared__ float Ss[64][65];
  __shared__ float mrow[64], lrow[64], arow[64];
  __shared__ int mk[64];

  const int bh = blockIdx.x;  // b*16+h
  const int b = bh >> 4;
  const int q0 = blockIdx.y * 64;
  const int t = threadIdx.x;

  const float* Qp = qb + ((size_t)bh * SB + q0) * HD;
#pragma unroll
  for (int i = 0; i < 16; i++) {   // 64x64 = 4096 elements = 16 * 256
    int f = t + i * 256;
    Qs[f >> 6][f & 63] = Qp[f];
  }
  if (t < 64) { mrow[t] = -INFINITY; lrow[t] = 0.f; }

  float o[16] = {};
  const int orow = t >> 2;
  const int od0 = (t & 3) * 16;
  const int tx = t & 15, ty = t >> 4;

  for (int kt = 0; kt < SB / 64; kt++) {
    __syncthreads();  // protect Ss/Vs from previous iteration's readers
#pragma unroll
    for (int i = 0; i < 16; i++) {  // 64x64 each for K and V
      int f = t + i * 256;
      int r = f >> 6, d = f & 63;
      size_t g = ((size_t)bh * SB + kt * 64 + r) * HD + d;
      Ks[r][d] = kb[g];
      Vs[r][d] = vb[g];
    }
    if (t < 64) mk[t] = mask[b * SB + kt * 64 + t];
    __syncthreads();

    // S = Q K^T * scale, 4x4 micro-tile per thread
    float acc[4][4] = {};
#pragma unroll 8
    for (int dd = 0; dd < 64; dd++) {
      float a[4], bv[4];
#pragma unroll
      for (int i = 0; i < 4; i++) a[i] = Qs[ty * 4 + i][dd];
#pragma unroll
      for (int j = 0; j < 4; j++) bv[j] = Ks[tx * 4 + j][dd];
#pragma unroll
      for (int i = 0; i < 4; i++)
#pragma unroll
        for (int j = 0; j < 4; j++) acc[i][j] += a[i] * bv[j];
    }
#pragma unroll
    for (int i = 0; i < 4; i++)
#pragma unroll
      for (int j = 0; j < 4; j++) {
        float sv = acc[i][j] * 0.125f;
        if (mk[tx * 4 + j] == 0) sv = -INFINITY;
        Ss[ty * 4 + i][tx * 4 + j] = sv;
      }
    __syncthreads();

    // Online softmax per row (threads 0..63)
    if (t < 64) {
      float m_old = mrow[t], m_new = m_old;
      for (int kk = 0; kk < 64; kk++) m_new = fmaxf(m_new, Ss[t][kk]);
      float al = expf(m_old - m_new);  // first iter: expf(-inf)=0
      float rs = 0.f;
      for (int kk = 0; kk < 64; kk++) {
        float p = expf(Ss[t][kk] - m_new);
        Ss[t][kk] = p;
        rs += p;
      }
      lrow[t] = lrow[t] * al + rs;
      mrow[t] = m_new;
      arow[t] = al;
    }
    __syncthreads();

    // O = O*alpha + P V
    float al = arow[orow];
#pragma unroll
    for (int j = 0; j < 16; j++) o[j] *= al;
    for (int kk = 0; kk < 64; kk++) {
      float p = Ss[orow][kk];
#pragma unroll
      for (int j = 0; j < 16; j++) o[j] += p * Vs[kk][od0 + j];
    }
  }

  const float linv = 1.f / lrow[orow];
  const int h = bh & 15;
  size_t base = ((size_t)b * SB + q0 + orow) * EB + h * HD + od0;
#pragma unroll
  for (int j = 0; j < 16; j++) ctx[base + j] = o[j] * linv;
}

// ---------------------------------------------------------------------------
// Kernel 3: out = ctx @ out_w^T + out_b. M=4096, N=1024, K=1024.
// ---------------------------------------------------------------------------
__global__ __launch_bounds__(256) void out_gemm(
    const float* __restrict__ cx, const float* __restrict__ w,
    const float* __restrict__ bias, float* __restrict__ out) {
  __shared__ float As[16][68];
  __shared__ float Bs[16][68];
  const int t = threadIdx.x;
  const int m0 = blockIdx.x * 64;
  const int n0 = blockIdx.y * 64;
  const int tx = t & 15, ty = t >> 4;
  float acc[4][4] = {};

  for (int k0 = 0; k0 < 1024; k0 += 16) {
#pragma unroll
    for (int i = 0; i < 4; i++) {
      int f = t + i * 256;
      int row = f >> 4, kk = f & 15;
      As[kk][row] = cx[(size_t)(m0 + row) * 1024 + k0 + kk];
      Bs[kk][row] = w[(size_t)(n0 + row) * 1024 + k0 + kk];
    }
    __syncthreads();
#pragma unroll
    for (int kk = 0; kk < 16; kk++) {
      float a[4], bv[4];
#pragma unroll
      for (int i = 0; i < 4; i++) a[i] = As[kk][ty * 4 + i];
#pragma unroll
      for (int j = 0; j < 4; j++) bv[j] = Bs[kk][tx * 4 + j];
#pragma unroll
      for (int i = 0; i < 4; i++)
#pragma unroll
        for (int j = 0; j < 4; j++) acc[i][j] += a[i] * bv[j];
    }
    __syncthreads();
  }

  float b4[4];
#pragma unroll
  for (int j = 0; j < 4; j++) b4[j] = bias[n0 + tx * 4 + j];
#pragma unroll
  for (int i = 0; i < 4; i++) {
    int m = m0 + ty * 4 + i;
#pragma unroll
    for (int j = 0; j < 4; j++)
      out[(size_t)m * 1024 + n0 + tx * 4 + j] = acc[i][j] + b4[j];
  }
}

extern "C" void kernel_launch(void* const* d_in, const int* in_sizes, int n_in,
                              void* d_out, int out_size, void* d_ws, size_t ws_size,
                              hipStream_t stream) {
  const float* x     = (const float*)d_in[0];
  const int* mask    = (const int*)d_in[1];
  const float* qkv_w = (const float*)d_in[2];
  const float* qkv_b = (const float*)d_in[3];
  const float* out_w = (const float*)d_in[4];
  const float* out_b = (const float*)d_in[5];
  float* out = (float*)d_out;

  float* ws = (float*)d_ws;
  float* qb = ws;                  // 2*16*2048*64 = 4,194,304 floats (16 MB)
  float* kb = ws + 4194304;
  float* vb = ws + 8388608;
  float* cx = ws + 12582912;       // context (B,S,E), 16 MB; total 64 MB

  dim3 blk(256);
  dim3 g1(64, 48);  // M/64 x N/64 for 4096x3072
  hipLaunchKernelGGL(qkv_gemm_rope, g1, blk, 0, stream, x, qkv_w, qkv_b, qb, kb, vb);

  dim3 g2(32, 32);  // (B*H) x (S/64)
  hipLaunchKernelGGL(attn_flash, g2, blk, 0, stream, qb, kb, vb, mask, cx);

  dim3 g3(64, 16);  // M/64 x N/64 for 4096x1024
  hipLaunchKernelGGL(out_gemm, g3, blk, 0, stream, cx, out_w, out_b, out);
}

// Round 3
// 760.980 us; speedup vs baseline: 1.9142x; 1.9142x over previous
//
#include <hip/hip_runtime.h>
#include <hip/hip_bf16.h>
#include <cmath>

// B=2, S=2048, E=1024, H=16, HD=64, ROT=64 (full-head RoPE)
#define SB 2048
#define EB 1024
#define NH 16
#define HD 64
#define KLOG 0.14391156831212788f  // ln(10000)/64

typedef unsigned short u16;
typedef unsigned int u32;
typedef __attribute__((ext_vector_type(8))) short short8;  // 8 bf16 (4 VGPRs)
typedef __attribute__((ext_vector_type(4))) float f32x4;

__device__ __forceinline__ u16 f2b(float x) {
  __hip_bfloat16 h = __float2bfloat16(x);
  return *reinterpret_cast<u16*>(&h);
}

// ---------------------------------------------------------------------------
// Kernel 1: qkv = x @ qkv_w^T + qkv_b (fp32 GEMM), fused RoPE, bf16 output
// scattered to (B,H,S,HD). M=4096, N=3072, K=1024.
// ---------------------------------------------------------------------------
__global__ __launch_bounds__(256) void qkv_gemm_rope(
    const float* __restrict__ x, const float* __restrict__ w,
    const float* __restrict__ bias, u16* __restrict__ qb,
    u16* __restrict__ kb, u16* __restrict__ vb) {
  __shared__ float As[16][68];
  __shared__ float Bs[16][68];
  const int t = threadIdx.x;
  const int m0 = blockIdx.x * 64;
  const int n0 = blockIdx.y * 64;
  const int tx = t & 15, ty = t >> 4;
  float acc[4][4] = {};

  for (int k0 = 0; k0 < 1024; k0 += 16) {
#pragma unroll
    for (int i = 0; i < 4; i++) {
      int f = t + i * 256;
      int row = f >> 4, kk = f & 15;
      As[kk][row] = x[(size_t)(m0 + row) * 1024 + k0 + kk];
      Bs[kk][row] = w[(size_t)(n0 + row) * 1024 + k0 + kk];
    }
    __syncthreads();
#pragma unroll
    for (int kk = 0; kk < 16; kk++) {
      float a[4], bv[4];
#pragma unroll
      for (int i = 0; i < 4; i++) a[i] = As[kk][ty * 4 + i];
#pragma unroll
      for (int j = 0; j < 4; j++) bv[j] = Bs[kk][tx * 4 + j];
#pragma unroll
      for (int i = 0; i < 4; i++)
#pragma unroll
        for (int j = 0; j < 4; j++) acc[i][j] += a[i] * bv[j];
    }
    __syncthreads();
  }

  const int c0 = n0 + tx * 4;
  const int which = c0 >> 10;      // 0=q 1=k 2=v
  const int e0 = c0 & 1023;
  const int h = e0 >> 6;
  const int d0 = e0 & 63;
  float b4[4];
#pragma unroll
  for (int j = 0; j < 4; j++) b4[j] = bias[c0 + j];

  const float inv0 = expf(-(float)d0 * KLOG);
  const float inv1 = expf(-(float)(d0 + 2) * KLOG);

#pragma unroll
  for (int i = 0; i < 4; i++) {
    int m = m0 + ty * 4 + i;
    int bb = m >> 11;
    int s = m & 2047;
    float v0 = acc[i][0] + b4[0];
    float v1 = acc[i][1] + b4[1];
    float v2 = acc[i][2] + b4[2];
    float v3 = acc[i][3] + b4[3];
    size_t off = ((size_t)(bb * NH + h) * SB + s) * HD + d0;  // mult of 4
    u32 p0, p1;
    u16* dst;
    if (which < 2) {
      float sn0, cs0, sn1, cs1;
      sincosf((float)s * inv0, &sn0, &cs0);
      sincosf((float)s * inv1, &sn1, &cs1);
      p0 = (u32)f2b(v0 * cs0 - v1 * sn0) | ((u32)f2b(v1 * cs0 + v0 * sn0) << 16);
      p1 = (u32)f2b(v2 * cs1 - v3 * sn1) | ((u32)f2b(v3 * cs1 + v2 * sn1) << 16);
      dst = (which == 0) ? qb : kb;
    } else {
      p0 = (u32)f2b(v0) | ((u32)f2b(v1) << 16);
      p1 = (u32)f2b(v2) | ((u32)f2b(v3) << 16);
      dst = vb;
    }
    uint2 pk = make_uint2(p0, p1);
    *(uint2*)&dst[off] = pk;   // 8-B aligned (off mult of 4 u16)
  }
}

// ---------------------------------------------------------------------------
// Kernel 2: flash attention, bf16 MFMA (16x16x32), fp32 softmax in-register.
// Block = 256 thr (4 waves) handles one (b,h) x 64 q-rows; K-tiles of 64.
// Wave w owns q-rows [16w,16w+16). O/S frags in C-layout; (m,l,alpha) state
// lives per (quad,reg) = per row, matching the C-layout exactly.
// ---------------------------------------------------------------------------
__global__ __launch_bounds__(256) void attn_mfma(
    const u16* __restrict__ qb, const u16* __restrict__ kb,
    const u16* __restrict__ vb, const int* __restrict__ mask,
    float* __restrict__ ctx) {
  __shared__ u16 Qs[64][72];  // [qrow][d]   pad 8 bf16 keeps b128 align
  __shared__ u16 Ks[64][72];  // [krow][d]
  __shared__ u16 Vt[64][72];  // [d][krow], XOR-swizzled blocks of 8
  __shared__ u16 Ps[64][72];  // [qrow][kcol] bf16 P
  __shared__ int mks[64];

  const int bh = blockIdx.x, b = bh >> 4, h = bh & 15;
  const int q0 = blockIdx.y * 64;
  const int t = threadIdx.x;
  const int lane = t & 63, wv = t >> 6;
  const int l15 = lane & 15, quad = lane >> 4;

  // stage Q (64x64 bf16), coalesced uint4
  {
    const u16* Qp = qb + ((size_t)bh * SB + q0) * HD;
#pragma unroll
    for (int i = 0; i < 2; i++) {
      int c = t + i * 256;            // chunk of 8 bf16
      int r = c >> 3, d0 = (c & 7) * 8;
      *(uint4*)&Qs[r][d0] = *(const uint4*)&Qp[c * 8];
    }
  }
  __syncthreads();
  short8 aq0 = *(const short8*)&Qs[wv * 16 + l15][quad * 8];
  short8 aq1 = *(const short8*)&Qs[wv * 16 + l15][32 + quad * 8];

  f32x4 o[4] = {{0,0,0,0},{0,0,0,0},{0,0,0,0},{0,0,0,0}};
  float m_i[4], l_i[4];
#pragma unroll
  for (int r = 0; r < 4; r++) { m_i[r] = -INFINITY; l_i[r] = 0.f; }

  for (int kt = 0; kt < SB / 64; kt++) {
    __syncthreads();  // prev iter's PV reads done before restage
    {
      const u16* Kp = kb + ((size_t)bh * SB + kt * 64) * HD;
      const u16* Vp = vb + ((size_t)bh * SB + kt * 64) * HD;
      // K: plain rows
#pragma unroll
      for (int i = 0; i < 2; i++) {
        int c = t + i * 256;
        int r = c >> 3, d0 = (c & 7) * 8;
        *(uint4*)&Ks[r][d0] = *(const uint4*)&Kp[c * 8];
      }
      // V: transpose into Vt[d][krow] with XOR swizzle; row-pairs packed as u32
      {
        int c = t;                    // 0..255
        int r0 = (c >> 3) * 2;        // even krow
        int cb = c & 7;               // = d>>3 for all 8 elems
        int d0 = cb * 8;
        uint4 va = *(const uint4*)&Vp[(size_t)r0 * HD + d0];
        uint4 vbv = *(const uint4*)&Vp[(size_t)(r0 + 1) * HD + d0];
        const u16* ua = (const u16*)&va;
        const u16* ub = (const u16*)&vbv;
        int pc = (((r0 >> 3) ^ cb) * 8) + (r0 & 7);  // even -> dword aligned
#pragma unroll
        for (int j = 0; j < 8; j++) {
          u32 pk = (u32)ua[j] | ((u32)ub[j] << 16);
          *(u32*)&Vt[d0 + j][pc] = pk;
        }
      }
      if (t < 64) mks[t] = mask[b * SB + kt * 64 + t];
    }
    __syncthreads();

    // S = Q K^T (B-frag: n=krow=nb*16+l15, k=d contiguous)
    f32x4 s[4] = {{0,0,0,0},{0,0,0,0},{0,0,0,0},{0,0,0,0}};
#pragma unroll
    for (int nb = 0; nb < 4; nb++) {
      short8 bk0 = *(const short8*)&Ks[nb * 16 + l15][quad * 8];
      short8 bk1 = *(const short8*)&Ks[nb * 16 + l15][32 + quad * 8];
      s[nb] = __builtin_amdgcn_mfma_f32_16x16x32_bf16(aq0, bk0, s[nb], 0, 0, 0);
      s[nb] = __builtin_amdgcn_mfma_f32_16x16x32_bf16(aq1, bk1, s[nb], 0, 0, 0);
    }
    int mkv[4];
#pragma unroll
    for (int nb = 0; nb < 4; nb++) mkv[nb] = mks[nb * 16 + l15];

    // online softmax per row (row = quad*4 + r), reduce over quad's 16 lanes
    float al[4];
#pragma unroll
    for (int r = 0; r < 4; r++) {
      float mx = -INFINITY;
#pragma unroll
      for (int nb = 0; nb < 4; nb++) {
        float sv = mkv[nb] ? s[nb][r] * 0.125f : -INFINITY;
        s[nb][r] = sv;
        mx = fmaxf(mx, sv);
      }
#pragma unroll
      for (int off = 1; off < 16; off <<= 1)
        mx = fmaxf(mx, __shfl_xor(mx, off, 64));
      float mn = fmaxf(m_i[r], mx);
      float a = (mn == -INFINITY) ? 1.f : __expf(m_i[r] - mn);
      float rs = 0.f;
#pragma unroll
      for (int nb = 0; nb < 4; nb++) {
        float p = (s[nb][r] == -INFINITY) ? 0.f : __expf(s[nb][r] - mn);
        s[nb][r] = p;
        rs += p;
      }
#pragma unroll
      for (int off = 1; off < 16; off <<= 1) rs += __shfl_xor(rs, off, 64);
      l_i[r] = l_i[r] * a + rs;
      m_i[r] = mn;
      al[r] = a;
    }

    // P -> LDS bf16 (C-layout scatter); each wave writes only its own 16 rows
#pragma unroll
    for (int nb = 0; nb < 4; nb++)
#pragma unroll
      for (int r = 0; r < 4; r++)
        Ps[wv * 16 + quad * 4 + r][nb * 16 + l15] = f2b(s[nb][r]);
    __syncthreads();

    // PV: A-frag from Ps (own rows), B-frag from swizzled Vt
    short8 pa0 = *(const short8*)&Ps[wv * 16 + l15][quad * 8];
    short8 pa1 = *(const short8*)&Ps[wv * 16 + l15][32 + quad * 8];
#pragma unroll
    for (int nb = 0; nb < 4; nb++) {
#pragma unroll
      for (int r = 0; r < 4; r++) o[nb][r] *= al[r];
      int dv = nb * 16 + l15;
      int pb0 = (quad) ^ (dv >> 3);       // kk=0: logical block quad
      int pb1 = (4 + quad) ^ (dv >> 3);   // kk=1: logical block 4+quad
      short8 vb0 = *(const short8*)&Vt[dv][pb0 * 8];
      short8 vb1 = *(const short8*)&Vt[dv][pb1 * 8];
      o[nb] = __builtin_amdgcn_mfma_f32_16x16x32_bf16(pa0, vb0, o[nb], 0, 0, 0);
      o[nb] = __builtin_amdgcn_mfma_f32_16x16x32_bf16(pa1, vb1, o[nb], 0, 0, 0);
    }
  }

  // epilogue: ctx[b, q0+row, h*64+col] fp32, row=wv*16+quad*4+r, col=nb*16+l15
#pragma unroll
  for (int r = 0; r < 4; r++) {
    float linv = 1.f / l_i[r];
    size_t base = ((size_t)b * SB + q0 + wv * 16 + quad * 4 + r) * EB + h * HD + l15;
#pragma unroll
    for (int nb = 0; nb < 4; nb++)
      ctx[base + nb * 16] = o[nb][r] * linv;
  }
}

// ---------------------------------------------------------------------------
// Kernel 3: out = ctx @ out_w^T + out_b (fp32). M=4096, N=1024, K=1024.
// ---------------------------------------------------------------------------
__global__ __launch_bounds__(256) void out_gemm(
    const float* __restrict__ cx, const float* __restrict__ w,
    const float* __restrict__ bias, float* __restrict__ out) {
  __shared__ float As[16][68];
  __shared__ float Bs[16][68];
  const int t = threadIdx.x;
  const int m0 = blockIdx.x * 64;
  const int n0 = blockIdx.y * 64;
  const int tx = t & 15, ty = t >> 4;
  float acc[4][4] = {};

  for (int k0 = 0; k0 < 1024; k0 += 16) {
#pragma unroll
    for (int i = 0; i < 4; i++) {
      int f = t + i * 256;
      int row = f >> 4, kk = f & 15;
      As[kk][row] = cx[(size_t)(m0 + row) * 1024 + k0 + kk];
      Bs[kk][row] = w[(size_t)(n0 + row) * 1024 + k0 + kk];
    }
    __syncthreads();
#pragma unroll
    for (int kk = 0; kk < 16; kk++) {
      float a[4], bv[4];
#pragma unroll
      for (int i = 0; i < 4; i++) a[i] = As[kk][ty * 4 + i];
#pragma unroll
      for (int j = 0; j < 4; j++) bv[j] = Bs[kk][tx * 4 + j];
#pragma unroll
      for (int i = 0; i < 4; i++)
#pragma unroll
        for (int j = 0; j < 4; j++) acc[i][j] += a[i] * bv[j];
    }
    __syncthreads();
  }

  float b4[4];
#pragma unroll
  for (int j = 0; j < 4; j++) b4[j] = bias[n0 + tx * 4 + j];
#pragma unroll
  for (int i = 0; i < 4; i++) {
    int m = m0 + ty * 4 + i;
#pragma unroll
    for (int j = 0; j < 4; j++)
      out[(size_t)m * 1024 + n0 + tx * 4 + j] = acc[i][j] + b4[j];
  }
}

extern "C" void kernel_launch(void* const* d_in, const int* in_sizes, int n_in,
                              void* d_out, int out_size, void* d_ws, size_t ws_size,
                              hipStream_t stream) {
  const float* x     = (const float*)d_in[0];
  const int* mask    = (const int*)d_in[1];
  const float* qkv_w = (const float*)d_in[2];
  const float* qkv_b = (const float*)d_in[3];
  const float* out_w = (const float*)d_in[4];
  const float* out_b = (const float*)d_in[5];
  float* out = (float*)d_out;

  char* wsb = (char*)d_ws;
  u16* qb   = (u16*)wsb;                       // 8 MB (4.19M bf16)
  u16* kb   = (u16*)(wsb + (8u << 20));        // 8 MB
  u16* vb   = (u16*)(wsb + (16u << 20));       // 8 MB
  float* cx = (float*)(wsb + (24u << 20));     // 16 MB -> total 40 MB

  dim3 blk(256);
  dim3 g1(64, 48);
  hipLaunchKernelGGL(qkv_gemm_rope, g1, blk, 0, stream, x, qkv_w, qkv_b, qb, kb, vb);

  dim3 g2(32, 32);  // (B*H) x (S/64)
  hipLaunchKernelGGL(attn_mfma, g2, blk, 0, stream, qb, kb, vb, mask, cx);

  dim3 g3(64, 16);
  hipLaunchKernelGGL(out_gemm, g3, blk, 0, stream, cx, out_w, out_b, out);
}

// Round 4
// 271.940 us; speedup vs baseline: 5.3566x; 2.7983x over previous
//
#include <hip/hip_runtime.h>
#include <hip/hip_bf16.h>
#include <cmath>

// B=2, S=2048, E=1024, H=16, HD=64, ROT=64 (full-head RoPE)
#define SB 2048
#define EB 1024
#define NH 16
#define HD 64
#define KLOG 0.14391156831212788f  // ln(10000)/64

typedef unsigned short u16;
typedef unsigned int u32;
typedef __attribute__((ext_vector_type(8))) short short8;  // 8 bf16 (4 VGPRs)
typedef __attribute__((ext_vector_type(4))) float f32x4;

__device__ __forceinline__ u16 f2b(float x) {
  __hip_bfloat16 h = __float2bfloat16(x);
  return *reinterpret_cast<u16*>(&h);
}

// async global->LDS, 16 B per lane. lptr MUST be wave-uniform; HW writes
// lane i's 16 B at lptr + i*16.
__device__ __forceinline__ void gl_lds16(const u16* g, u16* l) {
  __builtin_amdgcn_global_load_lds(
      (const __attribute__((address_space(1))) unsigned int*)g,
      (__attribute__((address_space(3))) unsigned int*)l, 16, 0, 0);
}

// ---------------------------------------------------------------------------
// fp32 -> bf16 elementwise convert (float4 in, ushort4 out)
// ---------------------------------------------------------------------------
__global__ __launch_bounds__(256) void conv_bf16(
    const float* __restrict__ src, u16* __restrict__ dst, int n4) {
  int i = blockIdx.x * blockDim.x + threadIdx.x;
  if (i < n4) {
    float4 v = ((const float4*)src)[i];
    ushort4 o;
    o.x = f2b(v.x); o.y = f2b(v.y); o.z = f2b(v.z); o.w = f2b(v.w);
    ((ushort4*)dst)[i] = o;
  }
}

// ---------------------------------------------------------------------------
// Kernel 1: qkv = x @ qkv_w^T (bf16 MFMA, fp32 acc) + bias, fused RoPE,
// bf16 out scattered to (B,H,S,HD). M=4096, N=3072, K=1024.
// 128x128 tile, BK=32, 4 waves (2x2 of 64x64), global_load_lds width=16.
// ---------------------------------------------------------------------------
__global__ __launch_bounds__(256) void qkv_mfma_rope(
    const u16* __restrict__ A, const u16* __restrict__ Bw,
    const float* __restrict__ bias, u16* __restrict__ qb,
    u16* __restrict__ kb, u16* __restrict__ vb) {
  __shared__ u16 As[128 * 32];   // row-major, stride 32 elem (64 B) — NO pad
  __shared__ u16 Bs[128 * 32];
  __shared__ float CS[128 * 32]; // RoPE table [row][pair]
  __shared__ float SN[128 * 32];

  const int t = threadIdx.x;
  const int lane = t & 63, wv = t >> 6;
  const int l15 = lane & 15, quad = lane >> 4;
  const int wm = wv >> 1, wn = wv & 1;
  const int m0 = blockIdx.x * 128;
  const int n0 = blockIdx.y * 128;

  f32x4 acc[4][4] = {};

  for (int k0 = 0; k0 < 1024; k0 += 32) {
    // stage: wave wv covers rows [wv*32, wv*32+32) of each tile, 2 calls of
    // 16 rows; lane i -> row i>>2, 16B-chunk i&3 (LDS contiguous == global)
#pragma unroll
    for (int c = 0; c < 2; c++) {
      int r = wv * 32 + c * 16;
      const u16* ga = A + (size_t)(m0 + r + (lane >> 2)) * 1024 + k0 + (lane & 3) * 8;
      const u16* gb = Bw + (size_t)(n0 + r + (lane >> 2)) * 1024 + k0 + (lane & 3) * 8;
      gl_lds16(ga, &As[r * 32]);
      gl_lds16(gb, &Bs[r * 32]);
    }
    __syncthreads();  // drains vmcnt before LDS reads

    short8 a[4], b[4];
#pragma unroll
    for (int mi = 0; mi < 4; mi++)
      a[mi] = *(const short8*)&As[(wm * 64 + mi * 16 + l15) * 32 + quad * 8];
#pragma unroll
    for (int ni = 0; ni < 4; ni++)
      b[ni] = *(const short8*)&Bs[(wn * 64 + ni * 16 + l15) * 32 + quad * 8];
#pragma unroll
    for (int mi = 0; mi < 4; mi++)
#pragma unroll
      for (int ni = 0; ni < 4; ni++)
        acc[mi][ni] = __builtin_amdgcn_mfma_f32_16x16x32_bf16(a[mi], b[ni], acc[mi][ni], 0, 0, 0);
    __syncthreads();  // all reads done before next stage overwrites
  }

  const int n_base = n0 + wn * 64;
  const int which = n_base >> 10;  // 0=q 1=k 2=v (uniform per block: 1024%128==0)
  float b4[4];
#pragma unroll
  for (int ni = 0; ni < 4; ni++) b4[ni] = bias[n_base + ni * 16 + l15];

  if (which < 2) {
    // RoPE table: CS/SN[row*32+p], row 0..127, pair p 0..31
#pragma unroll
    for (int i = 0; i < 16; i++) {
      int idx = t + i * 256;
      int row = idx >> 5, p = idx & 31;
      float spos = (float)((m0 & 2047) + row);
      float theta = spos * expf(-(float)(2 * p) * KLOG);
      float sn_, cs_;
      sincosf(theta, &sn_, &cs_);
      CS[idx] = cs_; SN[idx] = sn_;
    }
    __syncthreads();
  }

  u16* dst = (which == 0) ? qb : ((which == 1) ? kb : vb);
  const int h = (n_base & 1023) >> 6;
#pragma unroll
  for (int mi = 0; mi < 4; mi++) {
#pragma unroll
    for (int r = 0; r < 4; r++) {
      int row = wm * 64 + mi * 16 + quad * 4 + r;
      int m = m0 + row;
      int bb = m >> 11, s = m & 2047;
      size_t obase = ((size_t)(bb * NH + h) * SB + s) * HD;
#pragma unroll
      for (int ni = 0; ni < 4; ni++) {
        float v = acc[mi][ni][r] + b4[ni];
        int d = ni * 16 + l15;
        if (which < 2) {
          float pv = __shfl_xor(v, 1, 64);  // partner column d^1
          float c = CS[row * 32 + (d >> 1)];
          float sn_ = SN[row * 32 + (d >> 1)];
          v = v * c + pv * ((d & 1) ? sn_ : -sn_);
        }
        dst[obase + d] = f2b(v);
      }
    }
  }
}

// ---------------------------------------------------------------------------
// Kernel 2: flash attention, bf16 MFMA, fp32 softmax in-register.
// Unchanged from R3 except ctx output is bf16.
// ---------------------------------------------------------------------------
__global__ __launch_bounds__(256) void attn_mfma(
    const u16* __restrict__ qb, const u16* __restrict__ kb,
    const u16* __restrict__ vb, const int* __restrict__ mask,
    u16* __restrict__ ctx) {
  __shared__ u16 Qs[64][72];
  __shared__ u16 Ks[64][72];
  __shared__ u16 Vt[64][72];  // [d][krow], XOR-swizzled blocks of 8
  __shared__ u16 Ps[64][72];
  __shared__ int mks[64];

  const int bh = blockIdx.x, b = bh >> 4, h = bh & 15;
  const int q0 = blockIdx.y * 64;
  const int t = threadIdx.x;
  const int lane = t & 63, wv = t >> 6;
  const int l15 = lane & 15, quad = lane >> 4;

  {
    const u16* Qp = qb + ((size_t)bh * SB + q0) * HD;
#pragma unroll
    for (int i = 0; i < 2; i++) {
      int c = t + i * 256;
      int r = c >> 3, d0 = (c & 7) * 8;
      *(uint4*)&Qs[r][d0] = *(const uint4*)&Qp[c * 8];
    }
  }
  __syncthreads();
  short8 aq0 = *(const short8*)&Qs[wv * 16 + l15][quad * 8];
  short8 aq1 = *(const short8*)&Qs[wv * 16 + l15][32 + quad * 8];

  f32x4 o[4] = {{0,0,0,0},{0,0,0,0},{0,0,0,0},{0,0,0,0}};
  float m_i[4], l_i[4];
#pragma unroll
  for (int r = 0; r < 4; r++) { m_i[r] = -INFINITY; l_i[r] = 0.f; }

  for (int kt = 0; kt < SB / 64; kt++) {
    __syncthreads();
    {
      const u16* Kp = kb + ((size_t)bh * SB + kt * 64) * HD;
      const u16* Vp = vb + ((size_t)bh * SB + kt * 64) * HD;
#pragma unroll
      for (int i = 0; i < 2; i++) {
        int c = t + i * 256;
        int r = c >> 3, d0 = (c & 7) * 8;
        *(uint4*)&Ks[r][d0] = *(const uint4*)&Kp[c * 8];
      }
      {
        int c = t;
        int r0 = (c >> 3) * 2;
        int cb = c & 7;
        int d0 = cb * 8;
        uint4 va = *(const uint4*)&Vp[(size_t)r0 * HD + d0];
        uint4 vbv = *(const uint4*)&Vp[(size_t)(r0 + 1) * HD + d0];
        const u16* ua = (const u16*)&va;
        const u16* ub = (const u16*)&vbv;
        int pc = (((r0 >> 3) ^ cb) * 8) + (r0 & 7);
#pragma unroll
        for (int j = 0; j < 8; j++) {
          u32 pk = (u32)ua[j] | ((u32)ub[j] << 16);
          *(u32*)&Vt[d0 + j][pc] = pk;
        }
      }
      if (t < 64) mks[t] = mask[b * SB + kt * 64 + t];
    }
    __syncthreads();

    f32x4 s[4] = {{0,0,0,0},{0,0,0,0},{0,0,0,0},{0,0,0,0}};
#pragma unroll
    for (int nb = 0; nb < 4; nb++) {
      short8 bk0 = *(const short8*)&Ks[nb * 16 + l15][quad * 8];
      short8 bk1 = *(const short8*)&Ks[nb * 16 + l15][32 + quad * 8];
      s[nb] = __builtin_amdgcn_mfma_f32_16x16x32_bf16(aq0, bk0, s[nb], 0, 0, 0);
      s[nb] = __builtin_amdgcn_mfma_f32_16x16x32_bf16(aq1, bk1, s[nb], 0, 0, 0);
    }
    int mkv[4];
#pragma unroll
    for (int nb = 0; nb < 4; nb++) mkv[nb] = mks[nb * 16 + l15];

    float al[4];
#pragma unroll
    for (int r = 0; r < 4; r++) {
      float mx = -INFINITY;
#pragma unroll
      for (int nb = 0; nb < 4; nb++) {
        float sv = mkv[nb] ? s[nb][r] * 0.125f : -INFINITY;
        s[nb][r] = sv;
        mx = fmaxf(mx, sv);
      }
#pragma unroll
      for (int off = 1; off < 16; off <<= 1)
        mx = fmaxf(mx, __shfl_xor(mx, off, 64));
      float mn = fmaxf(m_i[r], mx);
      float a = (mn == -INFINITY) ? 1.f : __expf(m_i[r] - mn);
      float rs = 0.f;
#pragma unroll
      for (int nb = 0; nb < 4; nb++) {
        float p = (s[nb][r] == -INFINITY) ? 0.f : __expf(s[nb][r] - mn);
        s[nb][r] = p;
        rs += p;
      }
#pragma unroll
      for (int off = 1; off < 16; off <<= 1) rs += __shfl_xor(rs, off, 64);
      l_i[r] = l_i[r] * a + rs;
      m_i[r] = mn;
      al[r] = a;
    }

#pragma unroll
    for (int nb = 0; nb < 4; nb++)
#pragma unroll
      for (int r = 0; r < 4; r++)
        Ps[wv * 16 + quad * 4 + r][nb * 16 + l15] = f2b(s[nb][r]);
    __syncthreads();

    short8 pa0 = *(const short8*)&Ps[wv * 16 + l15][quad * 8];
    short8 pa1 = *(const short8*)&Ps[wv * 16 + l15][32 + quad * 8];
#pragma unroll
    for (int nb = 0; nb < 4; nb++) {
#pragma unroll
      for (int r = 0; r < 4; r++) o[nb][r] *= al[r];
      int dv = nb * 16 + l15;
      int pb0 = (quad) ^ (dv >> 3);
      int pb1 = (4 + quad) ^ (dv >> 3);
      short8 vb0 = *(const short8*)&Vt[dv][pb0 * 8];
      short8 vb1 = *(const short8*)&Vt[dv][pb1 * 8];
      o[nb] = __builtin_amdgcn_mfma_f32_16x16x32_bf16(pa0, vb0, o[nb], 0, 0, 0);
      o[nb] = __builtin_amdgcn_mfma_f32_16x16x32_bf16(pa1, vb1, o[nb], 0, 0, 0);
    }
  }

  // epilogue: ctx (B,S,E) bf16
#pragma unroll
  for (int r = 0; r < 4; r++) {
    float linv = 1.f / l_i[r];
    size_t base = ((size_t)b * SB + q0 + wv * 16 + quad * 4 + r) * EB + h * HD + l15;
#pragma unroll
    for (int nb = 0; nb < 4; nb++)
      ctx[base + nb * 16] = f2b(o[nb][r] * linv);
  }
}

// ---------------------------------------------------------------------------
// Kernel 3: out = ctx @ out_w^T + out_b (bf16 MFMA, fp32 out).
// M=4096, N=1024, K=1024. Same 128x128/BK=32 structure.
// ---------------------------------------------------------------------------
__global__ __launch_bounds__(256) void out_mfma(
    const u16* __restrict__ A, const u16* __restrict__ Bw,
    const float* __restrict__ bias, float* __restrict__ out) {
  __shared__ u16 As[128 * 32];
  __shared__ u16 Bs[128 * 32];

  const int t = threadIdx.x;
  const int lane = t & 63, wv = t >> 6;
  const int l15 = lane & 15, quad = lane >> 4;
  const int wm = wv >> 1, wn = wv & 1;
  const int m0 = blockIdx.x * 128;
  const int n0 = blockIdx.y * 128;

  f32x4 acc[4][4] = {};

  for (int k0 = 0; k0 < 1024; k0 += 32) {
#pragma unroll
    for (int c = 0; c < 2; c++) {
      int r = wv * 32 + c * 16;
      const u16* ga = A + (size_t)(m0 + r + (lane >> 2)) * 1024 + k0 + (lane & 3) * 8;
      const u16* gb = Bw + (size_t)(n0 + r + (lane >> 2)) * 1024 + k0 + (lane & 3) * 8;
      gl_lds16(ga, &As[r * 32]);
      gl_lds16(gb, &Bs[r * 32]);
    }
    __syncthreads();

    short8 a[4], b[4];
#pragma unroll
    for (int mi = 0; mi < 4; mi++)
      a[mi] = *(const short8*)&As[(wm * 64 + mi * 16 + l15) * 32 + quad * 8];
#pragma unroll
    for (int ni = 0; ni < 4; ni++)
      b[ni] = *(const short8*)&Bs[(wn * 64 + ni * 16 + l15) * 32 + quad * 8];
#pragma unroll
    for (int mi = 0; mi < 4; mi++)
#pragma unroll
      for (int ni = 0; ni < 4; ni++)
        acc[mi][ni] = __builtin_amdgcn_mfma_f32_16x16x32_bf16(a[mi], b[ni], acc[mi][ni], 0, 0, 0);
    __syncthreads();
  }

  float b4[4];
#pragma unroll
  for (int ni = 0; ni < 4; ni++) b4[ni] = bias[n0 + wn * 64 + ni * 16 + l15];
#pragma unroll
  for (int mi = 0; mi < 4; mi++)
#pragma unroll
    for (int r = 0; r < 4; r++) {
      int m = m0 + wm * 64 + mi * 16 + quad * 4 + r;
#pragma unroll
      for (int ni = 0; ni < 4; ni++)
        out[(size_t)m * 1024 + n0 + wn * 64 + ni * 16 + l15] = acc[mi][ni][r] + b4[ni];
    }
}

extern "C" void kernel_launch(void* const* d_in, const int* in_sizes, int n_in,
                              void* d_out, int out_size, void* d_ws, size_t ws_size,
                              hipStream_t stream) {
  const float* x     = (const float*)d_in[0];
  const int* mask    = (const int*)d_in[1];
  const float* qkv_w = (const float*)d_in[2];
  const float* qkv_b = (const float*)d_in[3];
  const float* out_w = (const float*)d_in[4];
  const float* out_b = (const float*)d_in[5];
  float* out = (float*)d_out;

  char* wsb = (char*)d_ws;
  u16* xb  = (u16*)wsb;                         // 8 MB  (4096x1024 bf16)
  u16* wqb = (u16*)(wsb + ( 8ull << 20));       // 6 MB  (3072x1024)
  u16* owb = (u16*)(wsb + (14ull << 20));       // 2 MB  (1024x1024)
  u16* qb  = (u16*)(wsb + (16ull << 20));       // 8 MB
  u16* kb  = (u16*)(wsb + (24ull << 20));       // 8 MB
  u16* vb  = (u16*)(wsb + (32ull << 20));       // 8 MB
  u16* cxb = (u16*)(wsb + (40ull << 20));       // 8 MB -> total 48 MB

  dim3 blk(256);
  hipLaunchKernelGGL(conv_bf16, dim3(4096), blk, 0, stream, x, xb, 4096 * 1024 / 4);
  hipLaunchKernelGGL(conv_bf16, dim3(3072), blk, 0, stream, qkv_w, wqb, 3072 * 1024 / 4);
  hipLaunchKernelGGL(conv_bf16, dim3(1024), blk, 0, stream, out_w, owb, 1024 * 1024 / 4);

  hipLaunchKernelGGL(qkv_mfma_rope, dim3(32, 24), blk, 0, stream,
                     xb, wqb, qkv_b, qb, kb, vb);

  hipLaunchKernelGGL(attn_mfma, dim3(32, 32), blk, 0, stream, qb, kb, vb, mask, cxb);

  hipLaunchKernelGGL(out_mfma, dim3(32, 8), blk, 0, stream, cxb, owb, out_b, out);
}

// Round 5
// 226.239 us; speedup vs baseline: 6.4387x; 1.2020x over previous
//
#include <hip/hip_runtime.h>
#include <hip/hip_bf16.h>
#include <cmath>

// B=2, S=2048, E=1024, H=16, HD=64, ROT=64 (full-head RoPE)
#define SB 2048
#define EB 1024
#define NH 16
#define HD 64
#define KLOG 0.14391156831212788f  // ln(10000)/64

typedef unsigned short u16;
typedef unsigned int u32;
typedef __attribute__((ext_vector_type(8))) short short8;  // 8 bf16 (4 VGPRs)
typedef __attribute__((ext_vector_type(4))) float f32x4;

__device__ __forceinline__ u16 f2b(float x) {
  __hip_bfloat16 h = __float2bfloat16(x);
  return *reinterpret_cast<u16*>(&h);
}

// async global->LDS, 16 B per lane; LDS side is wave-uniform base + lane*16.
__device__ __forceinline__ void gl_lds16(const u16* g, u16* l) {
  __builtin_amdgcn_global_load_lds(
      (const __attribute__((address_space(1))) unsigned int*)g,
      (__attribute__((address_space(3))) unsigned int*)l, 16, 0, 0);
}

// ---------------------------------------------------------------------------
// fp32 -> bf16 convert for x, qkv_w, out_w in ONE launch.
// ---------------------------------------------------------------------------
#define CN1 (4096 * 1024 / 4)
#define CN2 (3072 * 1024 / 4)
#define CN3 (1024 * 1024 / 4)
__global__ __launch_bounds__(256) void conv_all(
    const float* __restrict__ x, const float* __restrict__ w1,
    const float* __restrict__ w2, u16* __restrict__ xb,
    u16* __restrict__ wqb, u16* __restrict__ owb) {
  int i = blockIdx.x * 256 + threadIdx.x;
  const float* src;
  u16* dst;
  int j;
  if (i < CN1) { src = x; dst = xb; j = i; }
  else if (i < CN1 + CN2) { src = w1; dst = wqb; j = i - CN1; }
  else if (i < CN1 + CN2 + CN3) { src = w2; dst = owb; j = i - CN1 - CN2; }
  else return;
  float4 v = ((const float4*)src)[j];
  ushort4 o;
  o.x = f2b(v.x); o.y = f2b(v.y); o.z = f2b(v.z); o.w = f2b(v.w);
  ((ushort4*)dst)[j] = o;
}

// ---------------------------------------------------------------------------
// Kernel 1: qkv = x @ qkv_w^T (bf16 MFMA) + bias, fused RoPE.
// q: *0.125 (exact), row-major (B,H,S,HD). k: row-major. v: TRANSPOSED
// vt[bh][d][s]. M=4096, N=3072, K=1024. 128x128 tile, BK=32.
// ---------------------------------------------------------------------------
__global__ __launch_bounds__(256) void qkv_mfma_rope(
    const u16* __restrict__ A, const u16* __restrict__ Bw,
    const float* __restrict__ bias, u16* __restrict__ qb,
    u16* __restrict__ kb, u16* __restrict__ vt) {
  __shared__ u16 As[128 * 32];   // contiguous == global order (gl_lds16)
  __shared__ u16 Bs[128 * 32];
  __shared__ float CS[128 * 32]; // RoPE table [row][pair]
  __shared__ float SN[128 * 32];

  const int t = threadIdx.x;
  const int lane = t & 63, wv = t >> 6;
  const int l15 = lane & 15, quad = lane >> 4;
  const int wm = wv >> 1, wn = wv & 1;
  const int m0 = blockIdx.x * 128;
  const int n0 = blockIdx.y * 128;

  f32x4 acc[4][4] = {};

  for (int k0 = 0; k0 < 1024; k0 += 32) {
#pragma unroll
    for (int c = 0; c < 2; c++) {
      int r = wv * 32 + c * 16;
      const u16* ga = A + (size_t)(m0 + r + (lane >> 2)) * 1024 + k0 + (lane & 3) * 8;
      const u16* gb = Bw + (size_t)(n0 + r + (lane >> 2)) * 1024 + k0 + (lane & 3) * 8;
      gl_lds16(ga, &As[r * 32]);
      gl_lds16(gb, &Bs[r * 32]);
    }
    __syncthreads();

    short8 a[4], b[4];
#pragma unroll
    for (int mi = 0; mi < 4; mi++)
      a[mi] = *(const short8*)&As[(wm * 64 + mi * 16 + l15) * 32 + quad * 8];
#pragma unroll
    for (int ni = 0; ni < 4; ni++)
      b[ni] = *(const short8*)&Bs[(wn * 64 + ni * 16 + l15) * 32 + quad * 8];
#pragma unroll
    for (int mi = 0; mi < 4; mi++)
#pragma unroll
      for (int ni = 0; ni < 4; ni++)
        acc[mi][ni] = __builtin_amdgcn_mfma_f32_16x16x32_bf16(a[mi], b[ni], acc[mi][ni], 0, 0, 0);
    __syncthreads();
  }

  const int n_base = n0 + wn * 64;
  const int which = n_base >> 10;  // 0=q 1=k 2=v (uniform per wave)
  float b4[4];
#pragma unroll
  for (int ni = 0; ni < 4; ni++) b4[ni] = bias[n_base + ni * 16 + l15];

  if (which < 2) {
#pragma unroll
    for (int i = 0; i < 16; i++) {
      int idx = t + i * 256;
      int row = idx >> 5, p = idx & 31;
      float spos = (float)((m0 & 2047) + row);
      float theta = spos * expf(-(float)(2 * p) * KLOG);
      float sn_, cs_;
      sincosf(theta, &sn_, &cs_);
      CS[idx] = cs_; SN[idx] = sn_;
    }
    __syncthreads();
  }

  const int h = (n_base & 1023) >> 6;
#pragma unroll
  for (int mi = 0; mi < 4; mi++) {
#pragma unroll
    for (int r = 0; r < 4; r++) {
      int row = wm * 64 + mi * 16 + quad * 4 + r;
      int m = m0 + row;
      int bb = m >> 11, s = m & 2047;
      if (which < 2) {
        u16* dst = (which == 0) ? qb : kb;
        size_t obase = ((size_t)(bb * NH + h) * SB + s) * HD;
#pragma unroll
        for (int ni = 0; ni < 4; ni++) {
          float v = acc[mi][ni][r] + b4[ni];
          int d = ni * 16 + l15;
          float pv = __shfl_xor(v, 1, 64);  // partner column d^1
          float c = CS[row * 32 + (d >> 1)];
          float sn_ = SN[row * 32 + (d >> 1)];
          v = v * c + pv * ((d & 1) ? sn_ : -sn_);
          if (which == 0) v *= 0.125f;  // fold softmax scale into q (exact)
          dst[obase + d] = f2b(v);
        }
      } else {
        // v: store transposed vt[bh][d][s]
        size_t tbase = (size_t)(bb * NH + h) * HD;
#pragma unroll
        for (int ni = 0; ni < 4; ni++) {
          float v = acc[mi][ni][r] + b4[ni];
          int d = ni * 16 + l15;
          vt[(tbase + d) * SB + s] = f2b(v);
        }
      }
    }
  }
}

// ---------------------------------------------------------------------------
// Kernel 2: flash attention, S^T formulation.
// S^T = mfma(A=K, B=Q): krow in-lane (quad*4+r per 16-block), qrow = l15.
// Softmax: in-lane reduce over 16 krows + 2 quad-shuffles; one (m,l) per lane.
// P^T pairs -> wave-private Ps2 (u32) -> PV B-frags; O^T = mfma(A=Vt, B=P).
// Block = 4 waves x 32 qrows = 128 q-tile; K-tiles of 64.
// ---------------------------------------------------------------------------
__global__ __launch_bounds__(256) void attn_mfma(
    const u16* __restrict__ qb, const u16* __restrict__ kb,
    const u16* __restrict__ vt, const int* __restrict__ mask,
    u16* __restrict__ ctx) {
  __shared__ u16 Ks[64][72];       // [krow][d]
  __shared__ u16 Vt[64][72];       // [d][krow]
  __shared__ u32 Ps2[4][32][20];   // per-wave [krow-pair][qrow]
  __shared__ int mks[64];

  const int bh = blockIdx.x, b = bh >> 4, h = bh & 15;
  const int q0 = blockIdx.y * 128;
  const int t = threadIdx.x;
  const int lane = t & 63, wv = t >> 6;
  const int l15 = lane & 15, quad = lane >> 4;

  // Q B-frags straight from global (coalesced): qrow = q0 + wv*32 + qh*16 + l15
  short8 bq[2][2];
#pragma unroll
  for (int qh = 0; qh < 2; qh++) {
    const u16* qp = qb + ((size_t)bh * SB + q0 + wv * 32 + qh * 16 + l15) * HD;
#pragma unroll
    for (int kk = 0; kk < 2; kk++)
      bq[qh][kk] = *(const short8*)&qp[kk * 32 + quad * 8];
  }

  f32x4 o[2][4] = {};
  float m_i[2] = {-INFINITY, -INFINITY};
  float l_i[2] = {0.f, 0.f};

  for (int kt = 0; kt < SB / 64; kt++) {
    __syncthreads();  // prev iteration's frag reads complete
#pragma unroll
    for (int i = 0; i < 2; i++) {
      int idx = t + i * 256;
      int r = idx >> 3, c = idx & 7;
      *(uint4*)&Ks[r][c * 8] =
          *(const uint4*)&kb[((size_t)bh * SB + kt * 64 + r) * HD + c * 8];
      *(uint4*)&Vt[r][c * 8] =
          *(const uint4*)&vt[((size_t)bh * HD + r) * SB + kt * 64 + c * 8];
    }
    if (t < 64) mks[t] = mask[b * SB + kt * 64 + t];
    __syncthreads();

    short8 ak[4][2], av[4][2];
    int mk4[4][4];
#pragma unroll
    for (int mb = 0; mb < 4; mb++) {
#pragma unroll
      for (int kk = 0; kk < 2; kk++) {
        ak[mb][kk] = *(const short8*)&Ks[mb * 16 + l15][kk * 32 + quad * 8];
        av[mb][kk] = *(const short8*)&Vt[mb * 16 + l15][kk * 32 + quad * 8];
      }
      int4 mv = *(const int4*)&mks[mb * 16 + quad * 4];
      mk4[mb][0] = mv.x; mk4[mb][1] = mv.y; mk4[mb][2] = mv.z; mk4[mb][3] = mv.w;
    }

#pragma unroll
    for (int qh = 0; qh < 2; qh++) {
      // S^T: s[mb][r] = score(krow = mb*16+quad*4+r, qrow = l15)
      f32x4 s[4] = {};
#pragma unroll
      for (int mb = 0; mb < 4; mb++) {
        s[mb] = __builtin_amdgcn_mfma_f32_16x16x32_bf16(ak[mb][0], bq[qh][0], s[mb], 0, 0, 0);
        s[mb] = __builtin_amdgcn_mfma_f32_16x16x32_bf16(ak[mb][1], bq[qh][1], s[mb], 0, 0, 0);
      }
      float mx = -INFINITY;
#pragma unroll
      for (int mb = 0; mb < 4; mb++)
#pragma unroll
        for (int r = 0; r < 4; r++) {
          float sv = mk4[mb][r] ? s[mb][r] : -INFINITY;
          s[mb][r] = sv;
          mx = fmaxf(mx, sv);
        }
      mx = fmaxf(mx, __shfl_xor(mx, 16, 64));
      mx = fmaxf(mx, __shfl_xor(mx, 32, 64));
      float mn = fmaxf(m_i[qh], mx);
      float mn_s = (mn == -INFINITY) ? 0.f : mn;  // avoid inf-inf
      float a = __expf(m_i[qh] - mn_s);
      float rs = 0.f;
#pragma unroll
      for (int mb = 0; mb < 4; mb++)
#pragma unroll
        for (int r = 0; r < 4; r++) {
          float p = __expf(s[mb][r] - mn_s);
          s[mb][r] = p;
          rs += p;
        }
      rs += __shfl_xor(rs, 16, 64);
      rs += __shfl_xor(rs, 32, 64);
      l_i[qh] = l_i[qh] * a + rs;
      m_i[qh] = mn;

      // P^T krow-pairs -> Ps2 (wave-private, no barrier needed)
#pragma unroll
      for (int mb = 0; mb < 4; mb++)
#pragma unroll
        for (int pr = 0; pr < 2; pr++) {
          u32 pk = (u32)f2b(s[mb][2 * pr]) | ((u32)f2b(s[mb][2 * pr + 1]) << 16);
          Ps2[wv][mb * 8 + quad * 2 + pr][l15] = pk;
        }
      // PV B-frags: u32 j2 holds krows kk*32 + quad*8 + {2j2, 2j2+1}
      short8 pb[2];
#pragma unroll
      for (int kk = 0; kk < 2; kk++) {
        u32 w[4];
#pragma unroll
        for (int j = 0; j < 4; j++)
          w[j] = Ps2[wv][kk * 16 + quad * 4 + j][l15];
        pb[kk] = *(const short8*)w;
      }
      // O^T: o[qh][nb][r] = O(d = nb*16+quad*4+r, qrow = l15)
#pragma unroll
      for (int nb = 0; nb < 4; nb++) {
#pragma unroll
        for (int r = 0; r < 4; r++) o[qh][nb][r] *= a;
        o[qh][nb] = __builtin_amdgcn_mfma_f32_16x16x32_bf16(av[nb][0], pb[0], o[qh][nb], 0, 0, 0);
        o[qh][nb] = __builtin_amdgcn_mfma_f32_16x16x32_bf16(av[nb][1], pb[1], o[qh][nb], 0, 0, 0);
      }
    }
  }

  // epilogue: ctx (B,S,E) bf16; in-lane d-pairs pack to u32 stores
#pragma unroll
  for (int qh = 0; qh < 2; qh++) {
    float linv = 1.f / l_i[qh];
    int qrow = q0 + wv * 32 + qh * 16 + l15;
    size_t base = ((size_t)b * SB + qrow) * EB + h * HD;
#pragma unroll
    for (int nb = 0; nb < 4; nb++)
#pragma unroll
      for (int pr = 0; pr < 2; pr++) {
        int d = nb * 16 + quad * 4 + 2 * pr;
        u32 pk = (u32)f2b(o[qh][nb][2 * pr] * linv) |
                 ((u32)f2b(o[qh][nb][2 * pr + 1] * linv) << 16);
        *(u32*)&ctx[base + d] = pk;
      }
  }
}

// ---------------------------------------------------------------------------
// Kernel 3: out = ctx @ out_w^T + out_b (bf16 MFMA, fp32 out).
// M=4096, N=1024, K=1024. 128x128 tile, BK=32.
// ---------------------------------------------------------------------------
__global__ __launch_bounds__(256) void out_mfma(
    const u16* __restrict__ A, const u16* __restrict__ Bw,
    const float* __restrict__ bias, float* __restrict__ out) {
  __shared__ u16 As[128 * 32];
  __shared__ u16 Bs[128 * 32];

  const int t = threadIdx.x;
  const int lane = t & 63, wv = t >> 6;
  const int l15 = lane & 15, quad = lane >> 4;
  const int wm = wv >> 1, wn = wv & 1;
  const int m0 = blockIdx.x * 128;
  const int n0 = blockIdx.y * 128;

  f32x4 acc[4][4] = {};

  for (int k0 = 0; k0 < 1024; k0 += 32) {
#pragma unroll
    for (int c = 0; c < 2; c++) {
      int r = wv * 32 + c * 16;
      const u16* ga = A + (size_t)(m0 + r + (lane >> 2)) * 1024 + k0 + (lane & 3) * 8;
      const u16* gb = Bw + (size_t)(n0 + r + (lane >> 2)) * 1024 + k0 + (lane & 3) * 8;
      gl_lds16(ga, &As[r * 32]);
      gl_lds16(gb, &Bs[r * 32]);
    }
    __syncthreads();

    short8 a[4], b[4];
#pragma unroll
    for (int mi = 0; mi < 4; mi++)
      a[mi] = *(const short8*)&As[(wm * 64 + mi * 16 + l15) * 32 + quad * 8];
#pragma unroll
    for (int ni = 0; ni < 4; ni++)
      b[ni] = *(const short8*)&Bs[(wn * 64 + ni * 16 + l15) * 32 + quad * 8];
#pragma unroll
    for (int mi = 0; mi < 4; mi++)
#pragma unroll
      for (int ni = 0; ni < 4; ni++)
        acc[mi][ni] = __builtin_amdgcn_mfma_f32_16x16x32_bf16(a[mi], b[ni], acc[mi][ni], 0, 0, 0);
    __syncthreads();
  }

  float b4[4];
#pragma unroll
  for (int ni = 0; ni < 4; ni++) b4[ni] = bias[n0 + wn * 64 + ni * 16 + l15];
#pragma unroll
  for (int mi = 0; mi < 4; mi++)
#pragma unroll
    for (int r = 0; r < 4; r++) {
      int m = m0 + wm * 64 + mi * 16 + quad * 4 + r;
#pragma unroll
      for (int ni = 0; ni < 4; ni++)
        out[(size_t)m * 1024 + n0 + wn * 64 + ni * 16 + l15] = acc[mi][ni][r] + b4[ni];
    }
}

extern "C" void kernel_launch(void* const* d_in, const int* in_sizes, int n_in,
                              void* d_out, int out_size, void* d_ws, size_t ws_size,
                              hipStream_t stream) {
  const float* x     = (const float*)d_in[0];
  const int* mask    = (const int*)d_in[1];
  const float* qkv_w = (const float*)d_in[2];
  const float* qkv_b = (const float*)d_in[3];
  const float* out_w = (const float*)d_in[4];
  const float* out_b = (const float*)d_in[5];
  float* out = (float*)d_out;

  char* wsb = (char*)d_ws;
  u16* xb  = (u16*)wsb;                         // 8 MB  (4096x1024 bf16)
  u16* wqb = (u16*)(wsb + ( 8ull << 20));       // 6 MB  (3072x1024)
  u16* owb = (u16*)(wsb + (14ull << 20));       // 2 MB  (1024x1024)
  u16* qb  = (u16*)(wsb + (16ull << 20));       // 8 MB  (pre-scaled by 1/8)
  u16* kb  = (u16*)(wsb + (24ull << 20));       // 8 MB
  u16* vtb = (u16*)(wsb + (32ull << 20));       // 8 MB  (V transposed [bh][d][s])
  u16* cxb = (u16*)(wsb + (40ull << 20));       // 8 MB -> total 48 MB

  dim3 blk(256);
  hipLaunchKernelGGL(conv_all, dim3((CN1 + CN2 + CN3 + 255) / 256), blk, 0, stream,
                     x, qkv_w, out_w, xb, wqb, owb);

  hipLaunchKernelGGL(qkv_mfma_rope, dim3(32, 24), blk, 0, stream,
                     xb, wqb, qkv_b, qb, kb, vtb);

  hipLaunchKernelGGL(attn_mfma, dim3(32, 16), blk, 0, stream, qb, kb, vtb, mask, cxb);

  hipLaunchKernelGGL(out_mfma, dim3(32, 8), blk, 0, stream, cxb, owb, out_b, out);
}